// Round 1
// baseline (742.124 us; speedup 1.0000x reference)
//
#include <hip/hip_runtime.h>
#include <hip/hip_bf16.h>
#include <hip/hip_cooperative_groups.h>
#include <math.h>

namespace cg = cooperative_groups;

#define NN      6144
#define IN_DIM  512
#define CH      4
#define CDIM    64
#define NODE    256              // elements per node record
#define PR      8                // rows per projection block (768 proj blocks)
#define PBLK    (NN / PR)
#define MAXD    96               // max degree slot (mean ~31, ~12 sigma margin)
#define FBLK    1024             // cooperative grid: 4 blocks/CU x 256 CUs
#define NPB     (NN / FBLK)      // nodes per block in fused iter (=6)

typedef int v4i __attribute__((ext_vector_type(4)));

// float -> bf16 round-to-nearest-even
__device__ __forceinline__ unsigned short f2bf(float x) {
    union { float f; unsigned int u; } v; v.f = x;
    const unsigned int r = v.u + 0x7FFFu + ((v.u >> 16) & 1u);
    return (unsigned short)(r >> 16);
}
__device__ __forceinline__ float bflo(unsigned int u) {
    union { unsigned int u; float f; } v; v.u = u << 16; return v.f;
}
__device__ __forceinline__ float bfhi(unsigned int u) {
    union { unsigned int u; float f; } v; v.u = u & 0xFFFF0000u; return v.f;
}
__device__ __forceinline__ void unpack8(uint4 u, float* o) {
    o[0] = bflo(u.x); o[1] = bfhi(u.x);
    o[2] = bflo(u.y); o[3] = bfhi(u.y);
    o[4] = bflo(u.z); o[5] = bfhi(u.z);
    o[6] = bflo(u.w); o[7] = bfhi(u.w);
}

// DPP add: v += lane-permuted(v), zero DS ops (VALU-rate cross-lane).
// 0xB1 = quad_perm [1,0,3,2] (xor 1); 0x4E = quad_perm [2,3,0,1] (xor 2);
// 0x124 = row_ror:4; 0x128 = row_ror:8 (rotation-sum over 16-lane row).
template <int CTRL>
__device__ __forceinline__ float dppadd(float v) {
    return v + __int_as_float(
        __builtin_amdgcn_update_dpp(0, __float_as_int(v), CTRL, 0xF, 0xF, true));
}

// ---------------------------------------------------------------------------
// Fused: blocks [0,PBLK) = projection GEMM (+bias, L2-norm, bf16 store);
// blocks [PBLK,..) = adjacency->ELL compaction (HBM-bound, provides
// latency-hiding waves for the FMA-bound proj blocks).
// feats layout: bf16 [n][c][k], 512 B per node.
// ---------------------------------------------------------------------------
__global__ __launch_bounds__(256) void proj_ell_kernel(
    const float* __restrict__ feat,   // [N, IN_DIM]
    const float* __restrict__ W,      // [CH, IN_DIM, CDIM]
    const float* __restrict__ bias,   // [CH, 1, CDIM]
    const int*   __restrict__ adj,    // [N, N]
    unsigned short* __restrict__ outbf, // [N, CH*CDIM] bf16
    int*   __restrict__ deg,          // [N]
    int*   __restrict__ cols)         // [N, MAXD]
{
    __shared__ float lds[PR * IN_DIM];  // 16 KB
    const int t = threadIdx.x;

    if (blockIdx.x < PBLK) {
        const int row0 = blockIdx.x * PR;
        {
            const float4* src = (const float4*)(feat + (size_t)row0 * IN_DIM);
            float4* dst = (float4*)lds;
#pragma unroll
            for (int i = 0; i < (PR * IN_DIM / 4) / 256; ++i)
                dst[t + i * 256] = src[t + i * 256];
        }
        __syncthreads();

        const int g  = t >> 6;        // wave: rows row0 + g*2 + {0,1}
        const int q  = t & 63;
        const int c  = q >> 4;
        const int k0 = (q & 15) * 4;

        float acc[2][4];
#pragma unroll
        for (int r = 0; r < 2; ++r)
#pragma unroll
            for (int j = 0; j < 4; ++j) acc[r][j] = 0.0f;

        const float* Wc   = W + (size_t)c * IN_DIM * CDIM + k0;
        const float* arow = lds + g * 2 * IN_DIM;

        for (int d = 0; d < IN_DIM; d += 4) {
            const float4 w0 = *(const float4*)(Wc + (size_t)(d + 0) * CDIM);
            const float4 w1 = *(const float4*)(Wc + (size_t)(d + 1) * CDIM);
            const float4 w2 = *(const float4*)(Wc + (size_t)(d + 2) * CDIM);
            const float4 w3 = *(const float4*)(Wc + (size_t)(d + 3) * CDIM);
#pragma unroll
            for (int r = 0; r < 2; ++r) {
                const float4 a = *(const float4*)(arow + r * IN_DIM + d);
                acc[r][0] = fmaf(a.x, w0.x, fmaf(a.y, w1.x, fmaf(a.z, w2.x, fmaf(a.w, w3.x, acc[r][0]))));
                acc[r][1] = fmaf(a.x, w0.y, fmaf(a.y, w1.y, fmaf(a.z, w2.y, fmaf(a.w, w3.y, acc[r][1]))));
                acc[r][2] = fmaf(a.x, w0.z, fmaf(a.y, w1.z, fmaf(a.z, w2.z, fmaf(a.w, w3.z, acc[r][2]))));
                acc[r][3] = fmaf(a.x, w0.w, fmaf(a.y, w1.w, fmaf(a.z, w2.w, fmaf(a.w, w3.w, acc[r][3]))));
            }
        }

        const float4 bv = *(const float4*)(bias + c * CDIM + k0);
#pragma unroll
        for (int r = 0; r < 2; ++r) {
            acc[r][0] += bv.x; acc[r][1] += bv.y; acc[r][2] += bv.z; acc[r][3] += bv.w;
            float ss = acc[r][0] * acc[r][0] + acc[r][1] * acc[r][1]
                     + acc[r][2] * acc[r][2] + acc[r][3] * acc[r][3];
            ss += __shfl_xor(ss, 1, 64);
            ss += __shfl_xor(ss, 2, 64);
            ss += __shfl_xor(ss, 4, 64);
            ss += __shfl_xor(ss, 8, 64);
            const float rn = __builtin_amdgcn_rsqf(fmaxf(ss, 1e-24f));
            ushort4 res;
            res.x = f2bf(acc[r][0] * rn); res.y = f2bf(acc[r][1] * rn);
            res.z = f2bf(acc[r][2] * rn); res.w = f2bf(acc[r][3] * rn);
            *(ushort4*)(outbf + (size_t)(row0 + g * 2 + r) * NODE + c * CDIM + k0) = res;
        }
    } else {
        int* cnt = (int*)lds;
        const int n = blockIdx.x - PBLK;
        if (t == 0) *cnt = 0;
        __syncthreads();

        const v4i* row = (const v4i*)(adj + (size_t)n * NN);
        int* rowcols = cols + (size_t)n * MAXD;
        for (int i = t; i < NN / 4; i += 256) {
            const v4i v = __builtin_nontemporal_load(&row[i]);
            if (v.x | v.y | v.z | v.w) {
                const int base = i * 4;
                if (v.x) { int p = atomicAdd(cnt, 1); if (p < MAXD) rowcols[p] = base + 0; }
                if (v.y) { int p = atomicAdd(cnt, 1); if (p < MAXD) rowcols[p] = base + 1; }
                if (v.z) { int p = atomicAdd(cnt, 1); if (p < MAXD) rowcols[p] = base + 2; }
                if (v.w) { int p = atomicAdd(cnt, 1); if (p < MAXD) rowcols[p] = base + 3; }
            }
        }
        __syncthreads();
        if (t == 0) deg[n] = min(*cnt, MAXD);
    }
}

// ---------------------------------------------------------------------------
// One propagation step for one node, executed by one wave.
// Lane = nb*16 + cj (cj = c*4 + j): 16-element bf16 slice of neighbor nb's
// channel c, 32 B contiguous per lane (2 uint4 loads).
// Per 4-neighbor chunk: ALL cross-lane reduction via DPP (quad_perm for the
// j-reduce, row_ror:4/8 rotation-sum for the channel softmax) -> zero DS ops
// in the loop. Only the one-time cross-nb reduction (xor 16/32) uses shfl.
// Scores unit-dot in [-1,1] -> no max shift.
// ---------------------------------------------------------------------------
template <bool LAST>
__device__ __forceinline__ void iter_node(
    const unsigned short* __restrict__ fin,  // [N, 256] bf16
    unsigned short* __restrict__ fout,       // bf16 (used if !LAST)
    float* __restrict__ fout32,              // fp32 (used if LAST)
    const int* __restrict__ deg,
    const int* __restrict__ cols,
    const int n, const int nb, const int cj)
{
    float qv[16], av[16];
    {
        const uint4* qp = (const uint4*)(fin + (size_t)n * NODE + cj * 16);
        unpack8(qp[0], qv); unpack8(qp[1], qv + 8);
    }
#pragma unroll
    for (int i = 0; i < 16; ++i) av[i] = 0.0f;

    const int d = deg[n];
    const int* cl = cols + (size_t)n * MAXD;
    const int nch = (d + 3) >> 2;

    bool val = nb < d;
    uint4 fa, fb;
    {
        const int m = val ? cl[nb] : 0;
        const uint4* fp = (const uint4*)(fin + (size_t)m * NODE + cj * 16);
        fa = fp[0]; fb = fp[1];
    }

    for (int ch = 0; ch < nch; ++ch) {
        const bool more = (ch + 1 < nch);
        bool valn = false;
        uint4 ga, gb;
        if (more) {
            const int idx = (ch + 1) * 4 + nb;
            valn = idx < d;
            const int m2 = valn ? cl[idx] : 0;
            const uint4* gp = (const uint4*)(fin + (size_t)m2 * NODE + cj * 16);
            ga = gp[0]; gb = gp[1];
        }

        float fv[16];
        unpack8(fa, fv); unpack8(fb, fv + 8);

        float p = 0.0f;
#pragma unroll
        for (int i = 0; i < 16; ++i) p = fmaf(qv[i], fv[i], p);
        // j-reduce (lane bits 0-1): DPP quad_perm xor1, xor2
        p = dppadd<0xB1>(p);
        p = dppadd<0x4E>(p);
        // softmax across channels (lane bits 2-3): rotation-sum via row_ror
        const float e = __expf(p);
        float s = dppadd<0x124>(e);
        s = dppadd<0x128>(s);
        const float w = val ? e * __builtin_amdgcn_rcpf(s) : 0.0f;

#pragma unroll
        for (int i = 0; i < 16; ++i) av[i] = fmaf(w, fv[i], av[i]);

        if (more) { fa = ga; fb = gb; val = valn; }
    }

    // sum across the 4 neighbor groups (lane bits 4-5); pipelined swizzles
#pragma unroll
    for (int i = 0; i < 16; ++i) {
        av[i] += __shfl_xor(av[i], 16, 64);
        av[i] += __shfl_xor(av[i], 32, 64);
    }
    // add self once
#pragma unroll
    for (int i = 0; i < 16; ++i) av[i] += qv[i];

    // per-channel L2 norm: 16 lane-local squares, DPP j-reduce
    float ss = 0.0f;
#pragma unroll
    for (int i = 0; i < 16; ++i) ss = fmaf(av[i], av[i], ss);
    ss = dppadd<0xB1>(ss);
    ss = dppadd<0x4E>(ss);
    const float rn = __builtin_amdgcn_rsqf(fmaxf(ss, 1e-24f));

    // lane (nb,cj) writes elements cj*16 + nb*4 .. +4 (no dynamic indexing)
    const float4 s0 = make_float4(av[0]  * rn, av[1]  * rn, av[2]  * rn, av[3]  * rn);
    const float4 s1 = make_float4(av[4]  * rn, av[5]  * rn, av[6]  * rn, av[7]  * rn);
    const float4 s2 = make_float4(av[8]  * rn, av[9]  * rn, av[10] * rn, av[11] * rn);
    const float4 s3 = make_float4(av[12] * rn, av[13] * rn, av[14] * rn, av[15] * rn);
    const float4 o = (nb == 0) ? s0 : (nb == 1) ? s1 : (nb == 2) ? s2 : s3;

    if constexpr (LAST) {
        *(float4*)(fout32 + (size_t)n * NODE + cj * 16 + nb * 4) = o;
    } else {
        ushort4 ob;
        ob.x = f2bf(o.x); ob.y = f2bf(o.y); ob.z = f2bf(o.z); ob.w = f2bf(o.w);
        *(ushort4*)(fout + (size_t)n * NODE + cj * 16 + nb * 4) = ob;
    }
}

// Fallback (non-cooperative) single-iteration kernel: 4 rows/block, 1 wave/row.
template <bool LAST>
__global__ __launch_bounds__(256) void iter_kernel(
    const unsigned short* __restrict__ fin,
    unsigned short* __restrict__ fout,
    float* __restrict__ fout32,
    const int* __restrict__ deg,
    const int* __restrict__ cols)
{
    const int wv   = threadIdx.x >> 6;
    const int lane = threadIdx.x & 63;
    iter_node<LAST>(fin, fout, fout32, deg, cols,
                    blockIdx.x * 4 + wv, lane >> 4, lane & 15);
}

// ---------------------------------------------------------------------------
// Cooperative fused 3-iteration kernel: removes 2 kernel boundaries (launch +
// L2 writeback/invalidate + cache-cold restart of the 3.1 MB feats set).
// 1024 blocks x 256 threads, launch_bounds(256,4) caps VGPR at 128 ->
// 4 blocks/CU guaranteed co-resident (zero LDS), so cooperative launch is
// always satisfiable. Each block owns NPB=6 nodes; waves stride the slots.
// grid.sync() between iterations provides the producer->consumer ordering.
// ---------------------------------------------------------------------------
__global__ __launch_bounds__(256, 4) void fused_iter_kernel(
    unsigned short* __restrict__ fA,   // ping (input of iter 0)
    unsigned short* __restrict__ fB,   // pong
    float* __restrict__ out,           // fp32 final output
    const int* __restrict__ deg,
    const int* __restrict__ cols)
{
    cg::grid_group grid = cg::this_grid();
    const int wv   = threadIdx.x >> 6;
    const int lane = threadIdx.x & 63;
    const int nb   = lane >> 4;
    const int cj   = lane & 15;
    const int base = blockIdx.x * NPB;

    // iter 0: A -> B
    for (int s = wv; s < NPB; s += 4)
        iter_node<false>(fA, fB, nullptr, deg, cols, base + s, nb, cj);
    __threadfence();
    grid.sync();

    // iter 1: B -> A
    for (int s = wv; s < NPB; s += 4)
        iter_node<false>(fB, fA, nullptr, deg, cols, base + s, nb, cj);
    __threadfence();
    grid.sync();

    // iter 2: A -> out (fp32)
    for (int s = wv; s < NPB; s += 4)
        iter_node<true>(fA, nullptr, out, deg, cols, base + s, nb, cj);
}

extern "C" void kernel_launch(void* const* d_in, const int* in_sizes, int n_in,
                              void* d_out, int out_size, void* d_ws, size_t ws_size,
                              hipStream_t stream) {
    const float* features = (const float*)d_in[0];   // [6144, 512]
    const int*   adj      = (const int*)d_in[1];     // [6144, 6144]
    const float* W        = (const float*)d_in[2];   // [4, 512, 64]
    const float* b        = (const float*)d_in[3];   // [4, 1, 64]
    float* out = (float*)d_out;                      // [6144, 256] == [n][c][k] flat

    unsigned short* featsA = (unsigned short*)d_ws;          // N*256 bf16 (3.1 MB)
    unsigned short* featsB = featsA + (size_t)NN * NODE;
    int* deg  = (int*)(featsB + (size_t)NN * NODE);
    int* cols = deg + NN;                                    // N*MAXD ints

    proj_ell_kernel<<<PBLK + NN, 256, 0, stream>>>(features, W, b, adj,
                                                   featsA, deg, cols);

    {
        void* args[] = { (void*)&featsA, (void*)&featsB, (void*)&out,
                         (void*)&deg, (void*)&cols };
        hipError_t e = hipLaunchCooperativeKernel((const void*)fused_iter_kernel,
                                                  dim3(FBLK), dim3(256),
                                                  args, 0, stream);
        if (e != hipSuccess) {
            // fallback: original 3-dispatch path
            iter_kernel<false><<<NN / 4, 256, 0, stream>>>(featsA, featsB, nullptr, deg, cols);
            iter_kernel<false><<<NN / 4, 256, 0, stream>>>(featsB, featsA, nullptr, deg, cols);
            iter_kernel<true ><<<NN / 4, 256, 0, stream>>>(featsA, nullptr, out, deg, cols);
        }
    }
}

// Round 2
// 304.581 us; speedup vs baseline: 2.4365x; 2.4365x over previous
//
#include <hip/hip_runtime.h>
#include <hip/hip_bf16.h>
#include <math.h>

#define NN      6144
#define IN_DIM  512
#define CH      4
#define CDIM    64
#define NODE    256              // elements per node record
#define PR      8                // rows per projection block (768 proj blocks)
#define PBLK    (NN / PR)
#define MAXD    96               // max degree slot (mean ~31, ~12 sigma margin)

typedef int v4i __attribute__((ext_vector_type(4)));

// float -> bf16 round-to-nearest-even
__device__ __forceinline__ unsigned short f2bf(float x) {
    union { float f; unsigned int u; } v; v.f = x;
    const unsigned int r = v.u + 0x7FFFu + ((v.u >> 16) & 1u);
    return (unsigned short)(r >> 16);
}
__device__ __forceinline__ float bflo(unsigned int u) {
    union { unsigned int u; float f; } v; v.u = u << 16; return v.f;
}
__device__ __forceinline__ float bfhi(unsigned int u) {
    union { unsigned int u; float f; } v; v.u = u & 0xFFFF0000u; return v.f;
}
__device__ __forceinline__ void unpack8(uint4 u, float* o) {
    o[0] = bflo(u.x); o[1] = bfhi(u.x);
    o[2] = bflo(u.y); o[3] = bfhi(u.y);
    o[4] = bflo(u.z); o[5] = bfhi(u.z);
    o[6] = bflo(u.w); o[7] = bfhi(u.w);
}

// DPP add: v += lane-permuted(v), zero DS ops (VALU-rate cross-lane).
// 0xB1 = quad_perm [1,0,3,2] (xor 1); 0x4E = quad_perm [2,3,0,1] (xor 2);
// 0x124 = row_ror:4; 0x128 = row_ror:8 (rotation-sum over 16-lane row).
template <int CTRL>
__device__ __forceinline__ float dppadd(float v) {
    return v + __int_as_float(
        __builtin_amdgcn_update_dpp(0, __float_as_int(v), CTRL, 0xF, 0xF, true));
}

// ---------------------------------------------------------------------------
// Fused: blocks [0,PBLK) = projection GEMM (+bias, L2-norm, bf16 store);
// blocks [PBLK,..) = adjacency->ELL compaction (HBM-bound, provides
// latency-hiding waves for the FMA-bound proj blocks).
// feats layout: bf16 [n][c][k], 512 B per node.
// (byte-identical to the 294 us baseline version)
// ---------------------------------------------------------------------------
__global__ __launch_bounds__(256) void proj_ell_kernel(
    const float* __restrict__ feat,   // [N, IN_DIM]
    const float* __restrict__ W,      // [CH, IN_DIM, CDIM]
    const float* __restrict__ bias,   // [CH, 1, CDIM]
    const int*   __restrict__ adj,    // [N, N]
    unsigned short* __restrict__ outbf, // [N, CH*CDIM] bf16
    int*   __restrict__ deg,          // [N]
    int*   __restrict__ cols)         // [N, MAXD]
{
    __shared__ float lds[PR * IN_DIM];  // 16 KB
    const int t = threadIdx.x;

    if (blockIdx.x < PBLK) {
        const int row0 = blockIdx.x * PR;
        {
            const float4* src = (const float4*)(feat + (size_t)row0 * IN_DIM);
            float4* dst = (float4*)lds;
#pragma unroll
            for (int i = 0; i < (PR * IN_DIM / 4) / 256; ++i)
                dst[t + i * 256] = src[t + i * 256];
        }
        __syncthreads();

        const int g  = t >> 6;        // wave: rows row0 + g*2 + {0,1}
        const int q  = t & 63;
        const int c  = q >> 4;
        const int k0 = (q & 15) * 4;

        float acc[2][4];
#pragma unroll
        for (int r = 0; r < 2; ++r)
#pragma unroll
            for (int j = 0; j < 4; ++j) acc[r][j] = 0.0f;

        const float* Wc   = W + (size_t)c * IN_DIM * CDIM + k0;
        const float* arow = lds + g * 2 * IN_DIM;

        for (int d = 0; d < IN_DIM; d += 4) {
            const float4 w0 = *(const float4*)(Wc + (size_t)(d + 0) * CDIM);
            const float4 w1 = *(const float4*)(Wc + (size_t)(d + 1) * CDIM);
            const float4 w2 = *(const float4*)(Wc + (size_t)(d + 2) * CDIM);
            const float4 w3 = *(const float4*)(Wc + (size_t)(d + 3) * CDIM);
#pragma unroll
            for (int r = 0; r < 2; ++r) {
                const float4 a = *(const float4*)(arow + r * IN_DIM + d);
                acc[r][0] = fmaf(a.x, w0.x, fmaf(a.y, w1.x, fmaf(a.z, w2.x, fmaf(a.w, w3.x, acc[r][0]))));
                acc[r][1] = fmaf(a.x, w0.y, fmaf(a.y, w1.y, fmaf(a.z, w2.y, fmaf(a.w, w3.y, acc[r][1]))));
                acc[r][2] = fmaf(a.x, w0.z, fmaf(a.y, w1.z, fmaf(a.z, w2.z, fmaf(a.w, w3.z, acc[r][2]))));
                acc[r][3] = fmaf(a.x, w0.w, fmaf(a.y, w1.w, fmaf(a.z, w2.w, fmaf(a.w, w3.w, acc[r][3]))));
            }
        }

        const float4 bv = *(const float4*)(bias + c * CDIM + k0);
#pragma unroll
        for (int r = 0; r < 2; ++r) {
            acc[r][0] += bv.x; acc[r][1] += bv.y; acc[r][2] += bv.z; acc[r][3] += bv.w;
            float ss = acc[r][0] * acc[r][0] + acc[r][1] * acc[r][1]
                     + acc[r][2] * acc[r][2] + acc[r][3] * acc[r][3];
            ss += __shfl_xor(ss, 1, 64);
            ss += __shfl_xor(ss, 2, 64);
            ss += __shfl_xor(ss, 4, 64);
            ss += __shfl_xor(ss, 8, 64);
            const float rn = __builtin_amdgcn_rsqf(fmaxf(ss, 1e-24f));
            ushort4 res;
            res.x = f2bf(acc[r][0] * rn); res.y = f2bf(acc[r][1] * rn);
            res.z = f2bf(acc[r][2] * rn); res.w = f2bf(acc[r][3] * rn);
            *(ushort4*)(outbf + (size_t)(row0 + g * 2 + r) * NODE + c * CDIM + k0) = res;
        }
    } else {
        int* cnt = (int*)lds;
        const int n = blockIdx.x - PBLK;
        if (t == 0) *cnt = 0;
        __syncthreads();

        const v4i* row = (const v4i*)(adj + (size_t)n * NN);
        int* rowcols = cols + (size_t)n * MAXD;
        for (int i = t; i < NN / 4; i += 256) {
            const v4i v = __builtin_nontemporal_load(&row[i]);
            if (v.x | v.y | v.z | v.w) {
                const int base = i * 4;
                if (v.x) { int p = atomicAdd(cnt, 1); if (p < MAXD) rowcols[p] = base + 0; }
                if (v.y) { int p = atomicAdd(cnt, 1); if (p < MAXD) rowcols[p] = base + 1; }
                if (v.z) { int p = atomicAdd(cnt, 1); if (p < MAXD) rowcols[p] = base + 2; }
                if (v.w) { int p = atomicAdd(cnt, 1); if (p < MAXD) rowcols[p] = base + 3; }
            }
        }
        __syncthreads();
        if (t == 0) deg[n] = min(*cnt, MAXD);
    }
}

// ---------------------------------------------------------------------------
// One propagation step for one node, one wave.
// Lane = nb*16 + cj (cj = c*4 + j): 16-element bf16 slice of neighbor nb's
// channel c, 32 B contiguous per lane (2 uint4 loads).
// R2 changes vs the 294us baseline:
//  * software-pipeline DEPTH 4 on the neighbor-row gathers (4 named slots,
//    explicit rotation; no runtime-indexed arrays -> no scratch) so 4 chunk
//    gathers are in flight per wave (baseline had 1).
//  * col indices come from LDS (staged per-block), removing the global
//    4B index load from the front of every gather dependency chain.
// Cross-lane reduction all-DPP as before. Scores unit-dot -> no max shift.
// ---------------------------------------------------------------------------
template <bool LAST>
__device__ __forceinline__ void iter_node(
    const unsigned short* __restrict__ fin,  // [N, 256] bf16
    unsigned short* __restrict__ fout,       // bf16 (used if !LAST)
    float* __restrict__ fout32,              // fp32 (used if LAST)
    const int d,                             // degree of node n
    const int* __restrict__ cl,              // LDS col list of node n
    const int n, const int nb, const int cj)
{
    float qv[16], av[16];
    {
        const uint4* qp = (const uint4*)(fin + (size_t)n * NODE + cj * 16);
        unpack8(qp[0], qv); unpack8(qp[1], qv + 8);
    }
#pragma unroll
    for (int i = 0; i < 16; ++i) av[i] = 0.0f;

    const int nch = (d + 3) >> 2;

    uint4 a0, b0, a1, b1, a2, b2, a3, b3;
    bool v0 = false, v1 = false, v2 = false, v3 = false;

    // issue the 2 x dwordx4 gather for chunk `chk` into one slot
    auto issue = [&](int chk, uint4& A, uint4& B, bool& V) {
        const int idx = chk * 4 + nb;
        V = idx < d;
        const int m = V ? cl[idx] : 0;      // ds_read (LDS), not global
        const uint4* fp = (const uint4*)(fin + (size_t)m * NODE + cj * 16);
        A = fp[0]; B = fp[1];
    };

    // consume one slot: dot, channel-softmax, weighted accumulate
    auto consume = [&](const uint4& A, const uint4& B, bool V) {
        float fv[16];
        unpack8(A, fv); unpack8(B, fv + 8);
        float p = 0.0f;
#pragma unroll
        for (int i = 0; i < 16; ++i) p = fmaf(qv[i], fv[i], p);
        p = dppadd<0xB1>(p);            // j-reduce (lane bits 0-1)
        p = dppadd<0x4E>(p);
        const float e = __expf(p);
        float s = dppadd<0x124>(e);     // channel sum (lane bits 2-3)
        s = dppadd<0x128>(s);
        const float w = V ? e * __builtin_amdgcn_rcpf(s) : 0.0f;
#pragma unroll
        for (int i = 0; i < 16; ++i) av[i] = fmaf(w, fv[i], av[i]);
    };

    if (nch > 0) {
        issue(0, a0, b0, v0);
        if (1 < nch) issue(1, a1, b1, v1);
        if (2 < nch) issue(2, a2, b2, v2);
        if (3 < nch) issue(3, a3, b3, v3);
        int ch = 0;
        for (;;) {
            consume(a0, b0, v0);
            if (++ch == nch) break;
            if (ch + 3 < nch) issue(ch + 3, a0, b0, v0);
            consume(a1, b1, v1);
            if (++ch == nch) break;
            if (ch + 3 < nch) issue(ch + 3, a1, b1, v1);
            consume(a2, b2, v2);
            if (++ch == nch) break;
            if (ch + 3 < nch) issue(ch + 3, a2, b2, v2);
            consume(a3, b3, v3);
            if (++ch == nch) break;
            if (ch + 3 < nch) issue(ch + 3, a3, b3, v3);
        }
    }

    // sum across the 4 neighbor groups (lane bits 4-5)
#pragma unroll
    for (int i = 0; i < 16; ++i) {
        av[i] += __shfl_xor(av[i], 16, 64);
        av[i] += __shfl_xor(av[i], 32, 64);
    }
    // add self once
#pragma unroll
    for (int i = 0; i < 16; ++i) av[i] += qv[i];

    // per-channel L2 norm: 16 lane-local squares, DPP j-reduce
    float ss = 0.0f;
#pragma unroll
    for (int i = 0; i < 16; ++i) ss = fmaf(av[i], av[i], ss);
    ss = dppadd<0xB1>(ss);
    ss = dppadd<0x4E>(ss);
    const float rn = __builtin_amdgcn_rsqf(fmaxf(ss, 1e-24f));

    // lane (nb,cj) writes elements cj*16 + nb*4 .. +4 (no dynamic indexing)
    const float4 s0 = make_float4(av[0]  * rn, av[1]  * rn, av[2]  * rn, av[3]  * rn);
    const float4 s1 = make_float4(av[4]  * rn, av[5]  * rn, av[6]  * rn, av[7]  * rn);
    const float4 s2 = make_float4(av[8]  * rn, av[9]  * rn, av[10] * rn, av[11] * rn);
    const float4 s3 = make_float4(av[12] * rn, av[13] * rn, av[14] * rn, av[15] * rn);
    const float4 o = (nb == 0) ? s0 : (nb == 1) ? s1 : (nb == 2) ? s2 : s3;

    if constexpr (LAST) {
        *(float4*)(fout32 + (size_t)n * NODE + cj * 16 + nb * 4) = o;
    } else {
        ushort4 ob;
        ob.x = f2bf(o.x); ob.y = f2bf(o.y); ob.z = f2bf(o.z); ob.w = f2bf(o.w);
        *(ushort4*)(fout + (size_t)n * NODE + cj * 16 + nb * 4) = ob;
    }
}

// 4 rows/block, 1 wave/row; col lists staged in LDS.
template <bool LAST>
__global__ __launch_bounds__(256) void iter_kernel(
    const unsigned short* __restrict__ fin,
    unsigned short* __restrict__ fout,
    float* __restrict__ fout32,
    const int* __restrict__ deg,
    const int* __restrict__ cols)
{
    __shared__ int scl[4 * MAXD];
    __shared__ int sdeg[4];
    const int t = threadIdx.x;
    const int base = blockIdx.x * 4;

    if (t < 4) sdeg[t] = deg[base + t];
    for (int i = t; i < 4 * MAXD; i += 256)
        scl[i] = cols[(size_t)base * MAXD + i];   // 4 contiguous rows
    __syncthreads();

    const int wv   = t >> 6;
    const int lane = t & 63;
    iter_node<LAST>(fin, fout, fout32, sdeg[wv], scl + wv * MAXD,
                    base + wv, lane >> 4, lane & 15);
}

extern "C" void kernel_launch(void* const* d_in, const int* in_sizes, int n_in,
                              void* d_out, int out_size, void* d_ws, size_t ws_size,
                              hipStream_t stream) {
    const float* features = (const float*)d_in[0];   // [6144, 512]
    const int*   adj      = (const int*)d_in[1];     // [6144, 6144]
    const float* W        = (const float*)d_in[2];   // [4, 512, 64]
    const float* b        = (const float*)d_in[3];   // [4, 1, 64]
    float* out = (float*)d_out;                      // [6144, 256] == [n][c][k] flat

    unsigned short* featsA = (unsigned short*)d_ws;          // N*256 bf16 (3.1 MB)
    unsigned short* featsB = featsA + (size_t)NN * NODE;
    int* deg  = (int*)(featsB + (size_t)NN * NODE);
    int* cols = deg + NN;                                    // N*MAXD ints

    proj_ell_kernel<<<PBLK + NN, 256, 0, stream>>>(features, W, b, adj,
                                                   featsA, deg, cols);
    iter_kernel<false><<<NN / 4, 256, 0, stream>>>(featsA, featsB, nullptr, deg, cols);
    iter_kernel<false><<<NN / 4, 256, 0, stream>>>(featsB, featsA, nullptr, deg, cols);
    iter_kernel<true ><<<NN / 4, 256, 0, stream>>>(featsA, nullptr, out, deg, cols);
}

// Round 3
// 274.753 us; speedup vs baseline: 2.7011x; 1.1086x over previous
//
#include <hip/hip_runtime.h>
#include <hip/hip_bf16.h>
#include <math.h>

#define NN      6144
#define IN_DIM  512
#define CH      4
#define CDIM    64
#define NODE    256              // elements per node record
#define PR      16               // rows per projection block (384 proj blocks)
#define PBLK    (NN / PR)
#define MAXD    96               // max degree slot (mean ~31, ~12 sigma margin)

typedef int v4i __attribute__((ext_vector_type(4)));

// float -> bf16 round-to-nearest-even
__device__ __forceinline__ unsigned short f2bf(float x) {
    union { float f; unsigned int u; } v; v.f = x;
    const unsigned int r = v.u + 0x7FFFu + ((v.u >> 16) & 1u);
    return (unsigned short)(r >> 16);
}
__device__ __forceinline__ float bflo(unsigned int u) {
    union { unsigned int u; float f; } v; v.u = u << 16; return v.f;
}
__device__ __forceinline__ float bfhi(unsigned int u) {
    union { unsigned int u; float f; } v; v.u = u & 0xFFFF0000u; return v.f;
}
__device__ __forceinline__ void unpack8(uint4 u, float* o) {
    o[0] = bflo(u.x); o[1] = bfhi(u.x);
    o[2] = bflo(u.y); o[3] = bfhi(u.y);
    o[4] = bflo(u.z); o[5] = bfhi(u.z);
    o[6] = bflo(u.w); o[7] = bfhi(u.w);
}

// DPP add: v += lane-permuted(v), zero DS ops (VALU-rate cross-lane).
// 0xB1 = quad_perm [1,0,3,2] (xor 1); 0x4E = quad_perm [2,3,0,1] (xor 2);
// 0x124 = row_ror:4; 0x128 = row_ror:8 (rotation-sum over 16-lane row).
template <int CTRL>
__device__ __forceinline__ float dppadd(float v) {
    return v + __int_as_float(
        __builtin_amdgcn_update_dpp(0, __float_as_int(v), CTRL, 0xF, 0xF, true));
}

// ---------------------------------------------------------------------------
// Fused: blocks [0,PBLK) = projection GEMM (+bias, L2-norm, bf16 store);
// blocks [PBLK,..) = adjacency->ELL compaction (HBM-bound, provides
// latency-hiding waves for the FMA-bound proj blocks).
// R3: PR 8->16 (4 rows/wave, acc[4][4]) halves proj-wave count and thus the
// per-wave-redundant W stream; lockstep __syncthreads every 4 d-iters keeps
// the 4 waves of a block within 16KB in the W stream so L1 (32KB) serves
// 3 of the 4 waves (W address is wave-invariant). W L2 traffic model:
// 1.5GB -> ~190MB. FMA chain order per output element unchanged ->
// bit-identical results.
// feats layout: bf16 [n][c][k], 512 B per node.
// ---------------------------------------------------------------------------
__global__ __launch_bounds__(256) void proj_ell_kernel(
    const float* __restrict__ feat,   // [N, IN_DIM]
    const float* __restrict__ W,      // [CH, IN_DIM, CDIM]
    const float* __restrict__ bias,   // [CH, 1, CDIM]
    const int*   __restrict__ adj,    // [N, N]
    unsigned short* __restrict__ outbf, // [N, CH*CDIM] bf16
    int*   __restrict__ deg,          // [N]
    int*   __restrict__ cols)         // [N, MAXD]
{
    __shared__ float lds[PR * IN_DIM];  // 32 KB
    const int t = threadIdx.x;

    if (blockIdx.x < PBLK) {
        const int row0 = blockIdx.x * PR;
        {
            const float4* src = (const float4*)(feat + (size_t)row0 * IN_DIM);
            float4* dst = (float4*)lds;
#pragma unroll
            for (int i = 0; i < (PR * IN_DIM / 4) / 256; ++i)
                dst[t + i * 256] = src[t + i * 256];
        }
        __syncthreads();

        const int g  = t >> 6;        // wave: rows row0 + g*4 + {0..3}
        const int q  = t & 63;
        const int c  = q >> 4;
        const int k0 = (q & 15) * 4;

        float acc[4][4];
#pragma unroll
        for (int r = 0; r < 4; ++r)
#pragma unroll
            for (int j = 0; j < 4; ++j) acc[r][j] = 0.0f;

        const float* Wc   = W + (size_t)c * IN_DIM * CDIM + k0;
        const float* arow = lds + g * 4 * IN_DIM;

        for (int d = 0; d < IN_DIM; d += 4) {
            const float4 w0 = *(const float4*)(Wc + (size_t)(d + 0) * CDIM);
            const float4 w1 = *(const float4*)(Wc + (size_t)(d + 1) * CDIM);
            const float4 w2 = *(const float4*)(Wc + (size_t)(d + 2) * CDIM);
            const float4 w3 = *(const float4*)(Wc + (size_t)(d + 3) * CDIM);
#pragma unroll
            for (int r = 0; r < 4; ++r) {
                const float4 a = *(const float4*)(arow + r * IN_DIM + d);
                acc[r][0] = fmaf(a.x, w0.x, fmaf(a.y, w1.x, fmaf(a.z, w2.x, fmaf(a.w, w3.x, acc[r][0]))));
                acc[r][1] = fmaf(a.x, w0.y, fmaf(a.y, w1.y, fmaf(a.z, w2.y, fmaf(a.w, w3.y, acc[r][1]))));
                acc[r][2] = fmaf(a.x, w0.z, fmaf(a.y, w1.z, fmaf(a.z, w2.z, fmaf(a.w, w3.z, acc[r][2]))));
                acc[r][3] = fmaf(a.x, w0.w, fmaf(a.y, w1.w, fmaf(a.z, w2.w, fmaf(a.w, w3.w, acc[r][3]))));
            }
            // lockstep the block's 4 waves on the shared W stream (L1 reuse):
            // every 4 iterations (16KB of W), uniform control flow.
            if ((d & 15) == 12) __syncthreads();
        }

        const float4 bv = *(const float4*)(bias + c * CDIM + k0);
#pragma unroll
        for (int r = 0; r < 4; ++r) {
            acc[r][0] += bv.x; acc[r][1] += bv.y; acc[r][2] += bv.z; acc[r][3] += bv.w;
            float ss = acc[r][0] * acc[r][0] + acc[r][1] * acc[r][1]
                     + acc[r][2] * acc[r][2] + acc[r][3] * acc[r][3];
            ss += __shfl_xor(ss, 1, 64);
            ss += __shfl_xor(ss, 2, 64);
            ss += __shfl_xor(ss, 4, 64);
            ss += __shfl_xor(ss, 8, 64);
            const float rn = __builtin_amdgcn_rsqf(fmaxf(ss, 1e-24f));
            ushort4 res;
            res.x = f2bf(acc[r][0] * rn); res.y = f2bf(acc[r][1] * rn);
            res.z = f2bf(acc[r][2] * rn); res.w = f2bf(acc[r][3] * rn);
            *(ushort4*)(outbf + (size_t)(row0 + g * 4 + r) * NODE + c * CDIM + k0) = res;
        }
    } else {
        int* cnt = (int*)lds;
        const int n = blockIdx.x - PBLK;
        if (t == 0) *cnt = 0;
        __syncthreads();

        const v4i* row = (const v4i*)(adj + (size_t)n * NN);
        int* rowcols = cols + (size_t)n * MAXD;
        for (int i = t; i < NN / 4; i += 256) {
            const v4i v = __builtin_nontemporal_load(&row[i]);
            if (v.x | v.y | v.z | v.w) {
                const int base = i * 4;
                if (v.x) { int p = atomicAdd(cnt, 1); if (p < MAXD) rowcols[p] = base + 0; }
                if (v.y) { int p = atomicAdd(cnt, 1); if (p < MAXD) rowcols[p] = base + 1; }
                if (v.z) { int p = atomicAdd(cnt, 1); if (p < MAXD) rowcols[p] = base + 2; }
                if (v.w) { int p = atomicAdd(cnt, 1); if (p < MAXD) rowcols[p] = base + 3; }
            }
        }
        __syncthreads();
        if (t == 0) deg[n] = min(*cnt, MAXD);
    }
}

// ---------------------------------------------------------------------------
// Propagation iteration on bf16 feats (fp32 math). 4 rows/block, 1 wave/row.
// (reverted byte-identical to the R0 294us version — R2's pipeline/LDS
// staging regressed it 12 -> 15.5 us/iter)
// Lane = nb*16 + cj (cj = c*4 + j): 16-element bf16 slice of neighbor nb's
// channel c, 32 B contiguous per lane (2 uint4 loads).
// ---------------------------------------------------------------------------
template <bool LAST>
__global__ __launch_bounds__(256) void iter_kernel(
    const unsigned short* __restrict__ fin,  // [N, 256] bf16
    unsigned short* __restrict__ fout,       // bf16 (used if !LAST)
    float* __restrict__ fout32,              // fp32 (used if LAST)
    const int* __restrict__ deg,
    const int* __restrict__ cols)
{
    const int wv   = threadIdx.x >> 6;
    const int lane = threadIdx.x & 63;
    const int n    = blockIdx.x * 4 + wv;
    const int nb   = lane >> 4;       // neighbor slot 0..3
    const int cj   = lane & 15;       // c*4 + j

    float qv[16], av[16];
    {
        const uint4* qp = (const uint4*)(fin + (size_t)n * NODE + cj * 16);
        unpack8(qp[0], qv); unpack8(qp[1], qv + 8);
    }
#pragma unroll
    for (int i = 0; i < 16; ++i) av[i] = 0.0f;

    const int d = deg[n];
    const int* cl = cols + (size_t)n * MAXD;
    const int nch = (d + 3) >> 2;

    bool val = nb < d;
    uint4 fa, fb;
    {
        const int m = val ? cl[nb] : 0;
        const uint4* fp = (const uint4*)(fin + (size_t)m * NODE + cj * 16);
        fa = fp[0]; fb = fp[1];
    }

    for (int ch = 0; ch < nch; ++ch) {
        const bool more = (ch + 1 < nch);
        bool valn = false;
        uint4 ga, gb;
        if (more) {
            const int idx = (ch + 1) * 4 + nb;
            valn = idx < d;
            const int m2 = valn ? cl[idx] : 0;
            const uint4* gp = (const uint4*)(fin + (size_t)m2 * NODE + cj * 16);
            ga = gp[0]; gb = gp[1];
        }

        float fv[16];
        unpack8(fa, fv); unpack8(fb, fv + 8);

        float p = 0.0f;
#pragma unroll
        for (int i = 0; i < 16; ++i) p = fmaf(qv[i], fv[i], p);
        // j-reduce (lane bits 0-1): DPP quad_perm xor1, xor2
        p = dppadd<0xB1>(p);
        p = dppadd<0x4E>(p);
        // softmax across channels (lane bits 2-3): rotation-sum via row_ror
        const float e = __expf(p);
        float s = dppadd<0x124>(e);
        s = dppadd<0x128>(s);
        const float w = val ? e * __builtin_amdgcn_rcpf(s) : 0.0f;

#pragma unroll
        for (int i = 0; i < 16; ++i) av[i] = fmaf(w, fv[i], av[i]);

        if (more) { fa = ga; fb = gb; val = valn; }
    }

    // sum across the 4 neighbor groups (lane bits 4-5); pipelined swizzles
#pragma unroll
    for (int i = 0; i < 16; ++i) {
        av[i] += __shfl_xor(av[i], 16, 64);
        av[i] += __shfl_xor(av[i], 32, 64);
    }
    // add self once
#pragma unroll
    for (int i = 0; i < 16; ++i) av[i] += qv[i];

    // per-channel L2 norm: 16 lane-local squares, DPP j-reduce
    float ss = 0.0f;
#pragma unroll
    for (int i = 0; i < 16; ++i) ss = fmaf(av[i], av[i], ss);
    ss = dppadd<0xB1>(ss);
    ss = dppadd<0x4E>(ss);
    const float rn = __builtin_amdgcn_rsqf(fmaxf(ss, 1e-24f));

    // lane (nb,cj) writes elements cj*16 + nb*4 .. +4 (no dynamic indexing)
    const float4 s0 = make_float4(av[0]  * rn, av[1]  * rn, av[2]  * rn, av[3]  * rn);
    const float4 s1 = make_float4(av[4]  * rn, av[5]  * rn, av[6]  * rn, av[7]  * rn);
    const float4 s2 = make_float4(av[8]  * rn, av[9]  * rn, av[10] * rn, av[11] * rn);
    const float4 s3 = make_float4(av[12] * rn, av[13] * rn, av[14] * rn, av[15] * rn);
    const float4 o = (nb == 0) ? s0 : (nb == 1) ? s1 : (nb == 2) ? s2 : s3;

    if (LAST) {
        *(float4*)(fout32 + (size_t)n * NODE + cj * 16 + nb * 4) = o;
    } else {
        ushort4 ob;
        ob.x = f2bf(o.x); ob.y = f2bf(o.y); ob.z = f2bf(o.z); ob.w = f2bf(o.w);
        *(ushort4*)(fout + (size_t)n * NODE + cj * 16 + nb * 4) = ob;
    }
}

extern "C" void kernel_launch(void* const* d_in, const int* in_sizes, int n_in,
                              void* d_out, int out_size, void* d_ws, size_t ws_size,
                              hipStream_t stream) {
    const float* features = (const float*)d_in[0];   // [6144, 512]
    const int*   adj      = (const int*)d_in[1];     // [6144, 6144]
    const float* W        = (const float*)d_in[2];   // [4, 512, 64]
    const float* b        = (const float*)d_in[3];   // [4, 1, 64]
    float* out = (float*)d_out;                      // [6144, 256] == [n][c][k] flat

    unsigned short* featsA = (unsigned short*)d_ws;          // N*256 bf16 (3.1 MB)
    unsigned short* featsB = featsA + (size_t)NN * NODE;
    int* deg  = (int*)(featsB + (size_t)NN * NODE);
    int* cols = deg + NN;                                    // N*MAXD ints

    proj_ell_kernel<<<PBLK + NN, 256, 0, stream>>>(features, W, b, adj,
                                                   featsA, deg, cols);
    iter_kernel<false><<<NN / 4, 256, 0, stream>>>(featsA, featsB, nullptr, deg, cols);
    iter_kernel<false><<<NN / 4, 256, 0, stream>>>(featsB, featsA, nullptr, deg, cols);
    iter_kernel<true ><<<NN / 4, 256, 0, stream>>>(featsA, nullptr, out, deg, cols);
}